// Round 7
// baseline (79.662 us; speedup 1.0000x reference)
//
#include <hip/hip_runtime.h>

typedef unsigned short u16;
typedef __attribute__((ext_vector_type(8))) __bf16 bf16x8;
typedef __attribute__((ext_vector_type(4))) float f32x4;

#define GLOAD_LDS16(g, l)                                                                     \
  __builtin_amdgcn_global_load_lds((const __attribute__((address_space(1))) unsigned int*)(g), \
                                   (__attribute__((address_space(3))) unsigned int*)(l), 16, 0, 0)

static __device__ __forceinline__ u16 f2bf(float f) {
  unsigned int u = __float_as_uint(f);
  u += 0x7fffu + ((u >> 16) & 1u);   // round-to-nearest-even
  return (u16)(u >> 16);
}

// Constants for this problem instance
#define BATCH 32
#define NN 1024   // transform length (K and M of the GEMM)
#define MM 512    // columns (N of the GEMM)

// ---- kernel 1: DCT-III matrix, bf16, Mm[j][k] ----
__global__ void fill_m(u16* __restrict__ Mm) {
  int idx = blockIdx.x * 256 + threadIdx.x;
  if (idx >= NN * NN) return;
  int j = idx >> 10;
  int k = idx & (NN - 1);
  float v;
  if (k == 0) {
    v = 0.03125f;  // 1/sqrt(1024)
  } else {
    int p = (k * (2 * j + 1)) & 4095;              // phase mod 4096 (cos period)
    float ang = (float)p * 1.5339807878856412e-3f; // pi/2048
    v = 0.04419417382415922f * cosf(ang);          // sqrt(2/1024) * cos
  }
  Mm[idx] = f2bf(v);
}

// ---- kernel 2: transpose + convert: x[B][n][m] f32 -> xt[B][m][n] bf16 ----
__global__ void conv_t(const float* __restrict__ x, u16* __restrict__ xt) {
  __shared__ u16 tile[32][34];
  const int b = blockIdx.z;
  const int k0 = blockIdx.y << 5;
  const int c0 = blockIdx.x << 5;
  const int t = threadIdx.x;
  {
    const int r = t >> 3;
    const int c4 = (t & 7) << 2;
    const float4 v = *(const float4*)(x + ((size_t)b * NN + k0 + r) * MM + c0 + c4);
    tile[c4 + 0][r] = f2bf(v.x);
    tile[c4 + 1][r] = f2bf(v.y);
    tile[c4 + 2][r] = f2bf(v.z);
    tile[c4 + 3][r] = f2bf(v.w);
  }
  __syncthreads();
  {
    const int c = t >> 3;
    const int ko = (t & 7) << 2;
    ushort4 o;
    o.x = tile[c][ko + 0];
    o.y = tile[c][ko + 1];
    o.z = tile[c][ko + 2];
    o.w = tile[c][ko + 3];
    *(ushort4*)(xt + ((size_t)b * MM + c0 + c) * NN + k0 + ko) = o;
  }
}

// ---- kernel 3: 256x256x(BK=64) 8-wave GEMM, R3 staging schedule + latency-hidden frags ----
// C[b] = Mm * X[b].  A = Mm[j][k]; Bt = xt[b][c][k]; both bf16 k-contiguous.
// LDS: 2 buf x {A[256][64], B[256][64]}, XOR-swizzle f(r)=r&7 (pre-swizzled global
// source + linear global_load_lds dest; frag reads conflict-free, verified R2/R3: 0).
// Staging (R3 map, 2 tiles deep for B): tile t phases q=0..3 (C-quadrant q):
//   q0: issue A3(t+1)->buf[nxt];   q1: issue B0,B1,A0(t+2)->buf[cur]
//   q2: issue B2,A1(t+2);          q3: issue B3,A2(t+2)
// Gate at q3: vmcnt(7) (= the 7 tile-t+2 pieces issued this tile stay in flight;
// everything older — all of tile t+1 — drained). t==14: vmcnt(0). t==15: none.
// Frag latency hiding: af double-buffered by phase parity (prefetch slice q+1
// before q's barrier); bfr double-buffered by tile parity (tile t+1's 8 reads +
// af slice0(t+1) issued after the q3 gate, before the tile barrier).
// Region safety: every prefetched LDS region's next overwrite is >=1 barrier after
// its consuming MFMA cluster (hand-checked per phase).
// XCD co-schedule: 4 tm-sharers of each (tn,b) B-panel share wg&7 (R5: FETCH 133->41MB).
__global__ __launch_bounds__(512, 2) void gemm_idct(const u16* __restrict__ A,
                                                    const u16* __restrict__ Bt,
                                                    float* __restrict__ C) {
  __shared__ __align__(16) u16 sA[2][16384];  // 64 KiB
  __shared__ __align__(16) u16 sB[2][16384];  // 64 KiB
  // --- XCD-aware block decode ---
  const int wg   = blockIdx.x;
  const int xcd  = wg & 7;
  const int slot = wg >> 3;
  const int tm   = slot & 3;                   // M tile (j), 0..3
  const int pairId = ((slot >> 2) << 3) | xcd; // 0..63
  const int tn   = pairId & 1;                 // N tile (c), 0..1
  const int b    = pairId >> 1;                // batch 0..31

  const int t512 = threadIdx.x;
  const int wave = t512 >> 6, lane = t512 & 63;
  const int wm = wave >> 2, wn = wave & 3;   // 2 x 4 waves; per-wave out 128x64
  const int lhi = lane >> 4, llo = lane & 15;

  // --- staging map (pre-swizzled source, linear gload_lds dest) ---
  const int srow = t512 >> 3;                  // row-in-slice 0..63
  const int sdc  = (t512 & 7) ^ (srow & 7);    // pre-swizzled data chunk
  const u16* gA = A + (size_t)(tm * 256 + srow) * NN + sdc * 8;
  const u16* gB = Bt + ((size_t)b * MM + tn * 256 + srow) * NN + sdc * 8;
#define ISSUE_A(buf, q, tt) GLOAD_LDS16(gA + (size_t)(q) * 64 * NN + (tt) * 64, \
                                        &sA[buf][(q) * 4096 + t512 * 8])
#define ISSUE_B(buf, p, tt) GLOAD_LDS16(gB + (size_t)(p) * 64 * NN + (tt) * 64, \
                                        &sB[buf][(p) * 4096 + t512 * 8])

  // --- fragment register sets ---
  bf16x8 af0_[2][2], af1_[2][2];   // A frags [mf][ks], phase-parity double buffer
  bf16x8 bfr0[4][2], bfr1[4][2];   // B frags [nf][ks], tile-parity double buffer
  f32x4 acc[8][4] = {};

#define READ_AF(DST, BASE, slice)                                                        \
  do {                                                                                   \
    _Pragma("unroll") for (int mf = 0; mf < 2; ++mf)                                     \
      _Pragma("unroll") for (int ks = 0; ks < 2; ++ks) {                                 \
        const int ra = (slice) * 64 + wm * 32 + mf * 16 + llo;                           \
        DST[mf][ks] = *(const bf16x8*)&(BASE)[ra * 64 + (((ks << 2) | lhi) ^ (llo & 7)) * 8]; \
      }                                                                                  \
  } while (0)

#define READ_BFR(DST, BASE)                                                              \
  do {                                                                                   \
    _Pragma("unroll") for (int nf = 0; nf < 4; ++nf)                                     \
      _Pragma("unroll") for (int ks = 0; ks < 2; ++ks) {                                 \
        const int rb = wn * 64 + nf * 16 + llo;                                          \
        DST[nf][ks] = *(const bf16x8*)&(BASE)[rb * 64 + (((ks << 2) | lhi) ^ (llo & 7)) * 8]; \
      }                                                                                  \
  } while (0)

  // ks OUTER: same-accumulator dependency distance = 8 MFMAs (R4 fix, now in this structure)
#define MFMA_CLUSTER(q, AF, BFR)                                                         \
  do {                                                                                   \
    __builtin_amdgcn_s_setprio(1);                                                       \
    _Pragma("unroll") for (int ks = 0; ks < 2; ++ks)                                     \
      _Pragma("unroll") for (int mf = 0; mf < 2; ++mf)                                   \
        _Pragma("unroll") for (int nf = 0; nf < 4; ++nf)                                 \
          acc[((q) << 1) | mf][nf] = __builtin_amdgcn_mfma_f32_16x16x32_bf16(            \
              AF[mf][ks], BFR[nf][ks], acc[((q) << 1) | mf][nf], 0, 0, 0);               \
    __builtin_amdgcn_s_setprio(0);                                                       \
  } while (0)

#define SBAR()                              \
  do {                                      \
    __builtin_amdgcn_sched_barrier(0);      \
    __builtin_amdgcn_s_barrier();           \
    __builtin_amdgcn_sched_barrier(0);      \
  } while (0)

  // ---- prologue: tile0 (8 pieces) + tile1 minus A3 (7 pieces); gate; preload frags ----
  {
#pragma unroll
    for (int p = 0; p < 4; ++p) ISSUE_B(0, p, 0);
#pragma unroll
    for (int q = 0; q < 4; ++q) ISSUE_A(0, q, 0);
#pragma unroll
    for (int p = 0; p < 4; ++p) ISSUE_B(1, p, 1);
    ISSUE_A(1, 0, 1);
    ISSUE_A(1, 1, 1);
    ISSUE_A(1, 2, 1);
    asm volatile("s_waitcnt vmcnt(7)" ::: "memory");  // 15 issued, <=7 out -> tile0 landed
    READ_BFR(bfr0, &sB[0][0]);
    READ_AF(af0_, &sA[0][0], 0);
    SBAR();
  }

#define TILE_BODY(t, BFRC, BFRN)                                                  \
  do {                                                                            \
    const int cur = (t) & 1, nxt = cur ^ 1;                                       \
    const u16* lA = &sA[cur][0];                                                  \
    const u16* lB = &sB[cur][0];                                                  \
    const u16* lAn = &sA[nxt][0];                                                 \
    const u16* lBn = &sB[nxt][0];                                                 \
    (void)lB;                                                                     \
    /* q0 */                                                                      \
    if ((t) < 15) ISSUE_A(nxt, 3, (t) + 1);                                       \
    READ_AF(af1_, lA, 1);                                                         \
    MFMA_CLUSTER(0, af0_, BFRC);                                                  \
    SBAR();                                                                       \
    /* q1 */                                                                      \
    if ((t) < 14) { ISSUE_B(cur, 0, (t) + 2); ISSUE_B(cur, 1, (t) + 2); ISSUE_A(cur, 0, (t) + 2); } \
    READ_AF(af0_, lA, 2);                                                         \
    MFMA_CLUSTER(1, af1_, BFRC);                                                  \
    SBAR();                                                                       \
    /* q2 */                                                                      \
    if ((t) < 14) { ISSUE_B(cur, 2, (t) + 2); ISSUE_A(cur, 1, (t) + 2); }         \
    READ_AF(af1_, lA, 3);                                                         \
    MFMA_CLUSTER(2, af0_, BFRC);                                                  \
    SBAR();                                                                       \
    /* q3 */                                                                      \
    if ((t) < 14) { ISSUE_B(cur, 3, (t) + 2); ISSUE_A(cur, 2, (t) + 2); }         \
    MFMA_CLUSTER(3, af1_, BFRC);                                                  \
    if ((t) < 14)                                                                 \
      asm volatile("s_waitcnt vmcnt(7)" ::: "memory");                            \
    else if ((t) == 14)                                                           \
      asm volatile("s_waitcnt vmcnt(0)" ::: "memory");                            \
    if ((t) < 15) {                                                               \
      READ_BFR(BFRN, lBn);                                                        \
      READ_AF(af0_, lAn, 0);                                                      \
    }                                                                             \
    SBAR();                                                                       \
  } while (0)

  for (int t = 0; t < 16; t += 2) {
    TILE_BODY(t,     bfr0, bfr1);  // even tile uses bfr0, prefetches bfr1
    TILE_BODY(t + 1, bfr1, bfr0);  // odd tile uses bfr1, prefetches bfr0
  }

  // ---- epilogue: C/D layout col=lane&15, row=(lane>>4)*4+reg ----
  float* Cb = C + (size_t)b * NN * MM;
  const int jbase = tm * 256 + wm * 32 + lhi * 4;
  const int cbase = tn * 256 + wn * 64 + llo;
#pragma unroll
  for (int q = 0; q < 4; ++q)
#pragma unroll
    for (int mf = 0; mf < 2; ++mf)
#pragma unroll
      for (int nf = 0; nf < 4; ++nf) {
        const int j = jbase + q * 64 + mf * 16;
        const int c = cbase + nf * 16;
#pragma unroll
        for (int r = 0; r < 4; ++r)
          Cb[(size_t)(j + r) * MM + c] = acc[(q << 1) | mf][nf][r];
      }
#undef ISSUE_A
#undef ISSUE_B
#undef READ_AF
#undef READ_BFR
#undef MFMA_CLUSTER
#undef SBAR
#undef TILE_BODY
}

extern "C" void kernel_launch(void* const* d_in, const int* in_sizes, int n_in,
                              void* d_out, int out_size, void* d_ws, size_t ws_size,
                              hipStream_t stream) {
  const float* x = (const float*)d_in[0];
  float* out = (float*)d_out;
  u16* Mm = (u16*)d_ws;                          // NN*NN u16 = 2 MiB
  u16* xt = (u16*)d_ws + (size_t)NN * NN;        // BATCH*MM*NN u16 = 32 MiB

  fill_m<<<dim3((NN * NN) / 256), dim3(256), 0, stream>>>(Mm);
  conv_t<<<dim3(MM / 32, NN / 32, BATCH), dim3(256), 0, stream>>>(x, xt);
  gemm_idct<<<dim3(256), dim3(512), 0, stream>>>(Mm, xt, out);
}

// Round 8
// 50.265 us; speedup vs baseline: 1.5848x; 1.5848x over previous
//
#include <hip/hip_runtime.h>

typedef unsigned short u16;
typedef __attribute__((ext_vector_type(8))) __bf16 bf16x8;
typedef __attribute__((ext_vector_type(4))) float f32x4;

#define GLOAD_LDS16(g, l)                                                                     \
  __builtin_amdgcn_global_load_lds((const __attribute__((address_space(1))) unsigned int*)(g), \
                                   (__attribute__((address_space(3))) unsigned int*)(l), 16, 0, 0)

static __device__ __forceinline__ u16 f2bf(float f) {
  unsigned int u = __float_as_uint(f);
  u += 0x7fffu + ((u >> 16) & 1u);   // round-to-nearest-even
  return (u16)(u >> 16);
}

// Problem constants
#define BATCH 32
#define NN 1024   // transform length
#define MM 512    // columns
#define KH 512    // half transform length (K of each half-GEMM)

// ---- kernel 1: even/odd DCT-III half-matrices, bf16 ----
// E[j][p] = M[j][2p], O[j][p] = M[j][2p+1], j,p in [0,512)
// M[j][k] = (k==0 ? 1/32 : 0.0442*cos(pi*k*(2j+1)/2048))
__global__ void fill_eo(u16* __restrict__ E, u16* __restrict__ O) {
  int idx = blockIdx.x * 256 + threadIdx.x;  // 512*512
  int j = idx >> 9;
  int p = idx & 511;
  int tj = 2 * j + 1;
  float ve;
  if (p == 0) {
    ve = 0.03125f;  // 1/sqrt(1024)
  } else {
    int pe = (2 * p * tj) & 4095;
    ve = 0.04419417382415922f * cosf((float)pe * 1.5339807878856412e-3f);
  }
  int po = ((2 * p + 1) * tj) & 4095;
  float vo = 0.04419417382415922f * cosf((float)po * 1.5339807878856412e-3f);
  E[idx] = f2bf(ve);
  O[idx] = f2bf(vo);
}

// ---- kernel 2: transpose + convert + even/odd split ----
// x[B][k][c] f32 -> Xe[B][c][p]=x[2p][c], Xo[B][c][p]=x[2p+1][c] (bf16, p-contig)
__global__ void conv_t(const float* __restrict__ x, u16* __restrict__ xe,
                       u16* __restrict__ xo) {
  __shared__ u16 tile[32][34];
  const int b = blockIdx.z;
  const int k0 = blockIdx.y << 5;
  const int c0 = blockIdx.x << 5;
  const int t = threadIdx.x;
  {
    const int r = t >> 3;
    const int c4 = (t & 7) << 2;
    const float4 v = *(const float4*)(x + ((size_t)b * NN + k0 + r) * MM + c0 + c4);
    tile[c4 + 0][r] = f2bf(v.x);
    tile[c4 + 1][r] = f2bf(v.y);
    tile[c4 + 2][r] = f2bf(v.z);
    tile[c4 + 3][r] = f2bf(v.w);
  }
  __syncthreads();
  {
    const int c = t >> 3;
    const int ko = (t & 7) << 2;       // 0..28, step 4; k0+ko even
    const int p0 = (k0 + ko) >> 1;
    ushort2 e, o;
    e.x = tile[c][ko + 0]; e.y = tile[c][ko + 2];
    o.x = tile[c][ko + 1]; o.y = tile[c][ko + 3];
    const size_t rb = ((size_t)b * MM + c0 + c) * KH + p0;
    *(ushort2*)(xe + rb) = e;
    *(ushort2*)(xo + rb) = o;
  }
}

// ---- kernel 3: symmetry-halved GEMM (R2 structure) ----
// Ye = E*Xe, Yo = O*Xo (each 128jp x 128c tile, K=512, BK=64, single-buffered);
// out[j] = Ye+Yo, out[1023-j] = Ye-Yo.
// 256 threads / 4 waves (2x2, wave tile 64x64); LDS 64 KiB -> 2 blocks/CU.
// Swizzle (R2-verified, 0 conflicts): chunk pc of row r holds data chunk pc^(r&7);
// staged via pre-swizzled global source + linear global_load_lds dest.
// XCD decode (R5-verified): 4 tm-sharers of each (tn,b) X-panel share wg&7.
__global__ __launch_bounds__(256, 2) void gemm_idct(const u16* __restrict__ E,
                                                    const u16* __restrict__ O,
                                                    const u16* __restrict__ Xe,
                                                    const u16* __restrict__ Xo,
                                                    float* __restrict__ C) {
  __shared__ __align__(16) u16 sE[128 * 64];   // 16 KiB each
  __shared__ __align__(16) u16 sO[128 * 64];
  __shared__ __align__(16) u16 sXe[128 * 64];
  __shared__ __align__(16) u16 sXo[128 * 64];
  // --- XCD-aware decode: wg&7 = xcd; jp-tile varies fastest within an XCD ---
  const int wg   = blockIdx.x;
  const int xcd  = wg & 7;
  const int slot = wg >> 3;
  const int tm   = slot & 3;                    // jp tile 0..3
  const int pair = ((slot >> 2) << 3) | xcd;    // 0..127
  const int tn   = pair & 3;                    // c tile 0..3
  const int b    = pair >> 2;                   // batch 0..31

  const int t = threadIdx.x;
  const int wave = t >> 6, lane = t & 63;
  const int wr = wave >> 1, wc = wave & 1;      // 2x2 waves, 64x64 each
  const int lhi = lane >> 4, llo = lane & 15;

  // staging map: 32 rows/call; thread t -> row srow=t>>3, pre-swizzled chunk
  const int srow = t >> 3;
  const int sdc  = (t & 7) ^ (srow & 7);

  const u16* gE  = E  + (size_t)(tm * 128 + srow) * KH + sdc * 8;
  const u16* gO  = O  + (size_t)(tm * 128 + srow) * KH + sdc * 8;
  const u16* gXe = Xe + ((size_t)b * MM + tn * 128 + srow) * KH + sdc * 8;
  const u16* gXo = Xo + ((size_t)b * MM + tn * 128 + srow) * KH + sdc * 8;

  f32x4 accE[4][4] = {};
  f32x4 accO[4][4] = {};

  for (int kt = 0; kt < KH; kt += 64) {
#pragma unroll
    for (int c = 0; c < 4; ++c) {
      GLOAD_LDS16(gE  + kt + (size_t)(c * 32) * KH, &sE[c * 2048 + t * 8]);
      GLOAD_LDS16(gO  + kt + (size_t)(c * 32) * KH, &sO[c * 2048 + t * 8]);
      GLOAD_LDS16(gXe + kt + (size_t)(c * 32) * KH, &sXe[c * 2048 + t * 8]);
      GLOAD_LDS16(gXo + kt + (size_t)(c * 32) * KH, &sXo[c * 2048 + t * 8]);
    }
    __syncthreads();  // drain + tiles ready

    bf16x8 fe[4][2], fo[4][2], fxe[4][2], fxo[4][2];
#pragma unroll
    for (int i = 0; i < 4; ++i)
#pragma unroll
      for (int ks = 0; ks < 2; ++ks) {
        const int ra = wr * 64 + i * 16 + llo;   // E/O row (jp)
        const int rb = wc * 64 + i * 16 + llo;   // Xe/Xo row (c)
        const int ca = ((((ks << 2) | lhi)) ^ (llo & 7)) << 3;
        fe[i][ks]  = *(const bf16x8*)&sE[ra * 64 + ca];
        fo[i][ks]  = *(const bf16x8*)&sO[ra * 64 + ca];
        fxe[i][ks] = *(const bf16x8*)&sXe[rb * 64 + ca];
        fxo[i][ks] = *(const bf16x8*)&sXo[rb * 64 + ca];
      }
    // ks OUTER; within ks: 16 E-MFMAs then 16 O-MFMAs (same-acc distance 32)
#pragma unroll
    for (int ks = 0; ks < 2; ++ks) {
#pragma unroll
      for (int mi = 0; mi < 4; ++mi)
#pragma unroll
        for (int ni = 0; ni < 4; ++ni)
          accE[mi][ni] = __builtin_amdgcn_mfma_f32_16x16x32_bf16(
              fe[mi][ks], fxe[ni][ks], accE[mi][ni], 0, 0, 0);
#pragma unroll
      for (int mi = 0; mi < 4; ++mi)
#pragma unroll
        for (int ni = 0; ni < 4; ++ni)
          accO[mi][ni] = __builtin_amdgcn_mfma_f32_16x16x32_bf16(
              fo[mi][ks], fxo[ni][ks], accO[mi][ni], 0, 0, 0);
    }
    __syncthreads();  // protect LDS before next stage
  }

  // ---- epilogue: out[j] = Ye+Yo, out[1023-j] = Ye-Yo ----
  // C/D layout (m89-verified): col = lane&15, row = (lane>>4)*4 + reg
  float* Cb = C + (size_t)b * NN * MM;
  const int jhbase = tm * 128 + wr * 64 + lhi * 4;
  const int cbase  = tn * 128 + wc * 64 + llo;
#pragma unroll
  for (int mi = 0; mi < 4; ++mi)
#pragma unroll
    for (int ni = 0; ni < 4; ++ni) {
      const int jh = jhbase + mi * 16;
      const int c  = cbase + ni * 16;
#pragma unroll
      for (int r = 0; r < 4; ++r) {
        const float ye = accE[mi][ni][r];
        const float yo = accO[mi][ni][r];
        Cb[(size_t)(jh + r) * MM + c]            = ye + yo;
        Cb[(size_t)(NN - 1 - (jh + r)) * MM + c] = ye - yo;
      }
    }
}

extern "C" void kernel_launch(void* const* d_in, const int* in_sizes, int n_in,
                              void* d_out, int out_size, void* d_ws, size_t ws_size,
                              hipStream_t stream) {
  const float* x = (const float*)d_in[0];
  float* out = (float*)d_out;
  u16* E  = (u16*)d_ws;                                   // 512*512 u16 = 512 KiB
  u16* O  = E + (size_t)KH * KH;                          // 512 KiB
  u16* xe = O + (size_t)KH * KH;                          // 32*512*512 u16 = 16 MiB
  u16* xo = xe + (size_t)BATCH * MM * KH;                 // 16 MiB

  fill_eo<<<dim3((KH * KH) / 256), dim3(256), 0, stream>>>(E, O);
  conv_t<<<dim3(MM / 32, NN / 32, BATCH), dim3(256), 0, stream>>>(x, xe, xo);
  gemm_idct<<<dim3(512), dim3(256), 0, stream>>>(E, O, xe, xo, out);
}